// Round 1
// baseline (292.589 us; speedup 1.0000x reference)
//
#include <hip/hip_runtime.h>
#include <stdint.h>

#define B_TOT 16384
#define F_NUM 24
#define D_DIM 64
#define P_NUM 276
#define BT    32          // b-columns per block (MFMA N)
#define ROWP  1544        // 1536 + 8 pad -> row stride = 772 words = 4 mod 32 banks
#define NTH   512

typedef float f32x16 __attribute__((ext_vector_type(16)));
typedef short bf16x8 __attribute__((ext_vector_type(8)));

__device__ inline unsigned short f2bf(float f) {
    unsigned u = __float_as_uint(f);
    u += 0x7fffu + ((u >> 16) & 1u);      // round-to-nearest-even
    return (unsigned short)(u >> 16);
}
__device__ inline float bf2f(unsigned short h) {
    return __uint_as_float(((unsigned)h) << 16);
}

// Prepass: W[p][d][e] fp32 -> bf16 A-fragments for mfma_f32_32x32x16_bf16.
// slot = ((p*4 + kstep)*2 + mtile)*64 + lane, 8 elems/slot:
//   elem i = W[p][mtile*32 + (lane&31)][kstep*16 + (lane>>5)*8 + i]
__global__ void wprep(const float* __restrict__ W, unsigned short* __restrict__ afrag) {
    int tid = blockIdx.x * 256 + threadIdx.x;   // 0 .. 141311
    int p = tid >> 9;
    if (p >= P_NUM) return;
    int lane  = tid & 63;
    int mtile = (tid >> 6) & 1;
    int kstep = (tid >> 7) & 3;
    int d  = mtile * 32 + (lane & 31);
    int e0 = kstep * 16 + (lane >> 5) * 8;
    const float* src = W + ((size_t)p * 4096 + d * 64 + e0);
    unsigned short* dst = afrag + (size_t)tid * 8;
    float4 v0 = *(const float4*)(src);
    float4 v1 = *(const float4*)(src + 4);
    dst[0]=f2bf(v0.x); dst[1]=f2bf(v0.y); dst[2]=f2bf(v0.z); dst[3]=f2bf(v0.w);
    dst[4]=f2bf(v1.x); dst[5]=f2bf(v1.y); dst[6]=f2bf(v1.z); dst[7]=f2bf(v1.w);
}

// Main: out[b] = sum_f sum_d x[b,f,d] * V_f[b,d],
//       V_f[b,d] = sum_{j>f} sum_e W_{fj}[d,e] x[b,j,e]
// MFMA: A = W-frag (m = d within mtile), B = x-tile (n = b), K = e.
// Waves split (mtile, kstep); epilogue is linear in V so K-split partials just add.
__global__ __launch_bounds__(NTH) void fmfm_main(const float* __restrict__ x,
                                                 const unsigned short* __restrict__ afrag,
                                                 float* __restrict__ out) {
    __shared__ __align__(16) unsigned short xs[BT * ROWP];   // ~96.5 KB bf16 x-tile
    __shared__ float t_red[BT];
    int tid = threadIdx.x;
    int btile = blockIdx.x;

    // Stage 32 rows x 1536 fp32 (contiguous in global) -> bf16 LDS, padded rows.
    const float4* xg = (const float4*)(x + (size_t)btile * BT * (F_NUM * D_DIM));
    #pragma unroll
    for (int c = 0; c < (BT * 384) / NTH; ++c) {
        int it  = tid + c * NTH;
        int row = it / 384;
        int c4  = it % 384;
        float4 v = xg[it];
        ushort4 h;
        h.x = f2bf(v.x); h.y = f2bf(v.y); h.z = f2bf(v.z); h.w = f2bf(v.w);
        *(ushort4*)(&xs[row * ROWP + c4 * 4]) = h;
    }
    if (tid < BT) t_red[tid] = 0.0f;
    __syncthreads();

    int lane  = tid & 63;
    int wave  = tid >> 6;        // 0..7
    int mtile = wave & 1;        // d-half (M)
    int kstep = wave >> 1;       // 0..3, e-chunk of 16 (K)
    int bcol  = lane & 31;       // this lane's output row b
    int q     = lane >> 5;
    int abase = (kstep * 2 + mtile) * 64 + lane;     // afrag slot offset (+ p*512)
    int boff  = kstep * 16 + q * 8;                  // e offset within a field
    const unsigned short* xrow = xs + bcol * ROWP;

    float tacc = 0.0f;
    int p = 0;
    for (int f = 0; f < F_NUM - 1; ++f) {
        f32x16 acc;
        #pragma unroll
        for (int i = 0; i < 16; ++i) acc[i] = 0.0f;
        for (int j = f + 1; j < F_NUM; ++j, ++p) {
            bf16x8 a = *(const bf16x8*)(afrag + (size_t)(p * 512 + abase) * 8);
            bf16x8 b = *(const bf16x8*)(xrow + j * 64 + boff);
            acc = __builtin_amdgcn_mfma_f32_32x32x16_bf16(a, b, acc, 0, 0, 0);
        }
        // epilogue: V rows d = mtile*32 + (reg&3) + 8*(reg>>2) + 4*q ; col = bcol
        int ebase = f * 64 + mtile * 32 + 4 * q;
        #pragma unroll
        for (int g = 0; g < 4; ++g) {
            ushort4 xe = *(const ushort4*)(xrow + ebase + 8 * g);   // 4 consecutive d
            tacc += acc[4*g+0] * bf2f(xe.x)
                  + acc[4*g+1] * bf2f(xe.y)
                  + acc[4*g+2] * bf2f(xe.z)
                  + acc[4*g+3] * bf2f(xe.w);
        }
    }
    atomicAdd(&t_red[bcol], tacc);
    __syncthreads();
    if (tid < BT) out[(size_t)btile * BT + tid] = t_red[tid];
}

extern "C" void kernel_launch(void* const* d_in, const int* in_sizes, int n_in,
                              void* d_out, int out_size, void* d_ws, size_t ws_size,
                              hipStream_t stream) {
    const float* x = (const float*)d_in[0];
    const float* W = (const float*)d_in[1];
    float* out = (float*)d_out;
    unsigned short* afrag = (unsigned short*)d_ws;   // 2.26 MB of scratch
    wprep<<<552, 256, 0, stream>>>(W, afrag);        // 552*256 = 141312 slots
    fmfm_main<<<B_TOT / BT, NTH, 0, stream>>>(x, afrag, out);
}

// Round 2
// 192.047 us; speedup vs baseline: 1.5235x; 1.5235x over previous
//
#include <hip/hip_runtime.h>
#include <stdint.h>

#define B_TOT 16384
#define F_NUM 24
#define D_DIM 64
#define P_NUM 276
#define BT    32          // b-columns per block (MFMA N)
#define ROWP  1544        // 1536 + 8 pad shorts
#define NTH   512

typedef float f32x16 __attribute__((ext_vector_type(16)));
typedef short bf16x8 __attribute__((ext_vector_type(8)));

__device__ inline unsigned short f2bf(float f) {
    unsigned u = __float_as_uint(f);
    u += 0x7fffu + ((u >> 16) & 1u);      // round-to-nearest-even
    return (unsigned short)(u >> 16);
}
__device__ inline float bf2f(unsigned short h) {
    return __uint_as_float(((unsigned)h) << 16);
}

// ---------------- pair schedule: fields partitioned across 8 waves ----------
// pair counts per field f: 23-f.  Balanced groups (34,34,34,34,34,34,36,36).
// entry = p | (j<<9) | (f<<14);  every field's last pair has j==23 (epilogue trigger)
struct WTab { int ent[8][36]; };
constexpr WTab build_tab() {
    WTab t{};
    const int fl[8][6] = {
        {0,12,-1,-1,-1,-1},
        {1,11,-1,-1,-1,-1},
        {2,10,-1,-1,-1,-1},
        {3, 9,-1,-1,-1,-1},
        {4, 8,-1,-1,-1,-1},
        {5, 7,-1,-1,-1,-1},
        {6,14,17,20,22,-1},
        {13,15,16,18,19,21}};
    for (int w = 0; w < 8; ++w) {
        int c = 0;
        for (int k = 0; k < 6; ++k) {
            int f = fl[w][k];
            if (f < 0) break;
            int base = 23 * f - f * (f - 1) / 2;      // p of pair (f, f+1)
            for (int j = f + 1; j < 24; ++j)
                t.ent[w][c++] = (base + j - f - 1) | (j << 9) | (f << 14);
        }
        int last = t.ent[w][c - 1];
        while (c < 36) t.ent[w][c++] = last;          // pad (never executed)
    }
    return t;
}
__device__ __constant__ WTab gtab = build_tab();

// ---------------- prepass: W fp32 -> bf16 A-fragments, fully coalesced ------
// afrag slot = (p*8 + u)*64 + lane, u = kstep*2 + mtile, 8 shorts/slot:
//   elem i = W[p][mtile*32 + (lane&31)][kstep*16 + (lane>>5)*8 + i]
__global__ __launch_bounds__(256) void wprep(const float* __restrict__ W,
                                             unsigned short* __restrict__ afrag) {
    __shared__ __align__(16) unsigned short wlds[64 * 72];   // pad 64->72 shorts
    int p = blockIdx.x, t = threadIdx.x;
    const float4* src = (const float4*)(W + (size_t)p * 4096);
    #pragma unroll
    for (int c = 0; c < 4; ++c) {
        int i = t + c * 256;             // float4 index 0..1023 (coalesced)
        float4 v = src[i];
        int d = i >> 4;
        int e = (i & 15) * 4;
        ushort4 h; h.x=f2bf(v.x); h.y=f2bf(v.y); h.z=f2bf(v.z); h.w=f2bf(v.w);
        *(ushort4*)(&wlds[d * 72 + e]) = h;
    }
    __syncthreads();
    unsigned short* dst = afrag + (size_t)p * 4096;
    #pragma unroll
    for (int c = 0; c < 2; ++c) {
        int sl = t + c * 256;            // slot-lane 0..511
        int u = sl >> 6, lane = sl & 63;
        int m = u & 1, ks = u >> 1;
        int d = m * 32 + (lane & 31);
        int e = ks * 16 + (lane >> 5) * 8;
        bf16x8 v = *(const bf16x8*)(&wlds[d * 72 + e]);
        *(bf16x8*)(dst + (size_t)sl * 8) = v;        // consecutive 16B: coalesced
    }
}

// ---------------- main kernel ----------------------------------------------
__global__ __launch_bounds__(NTH, 2) void fmfm_main(const float* __restrict__ x,
                                                    const unsigned short* __restrict__ afrag,
                                                    float* __restrict__ out) {
    __shared__ __align__(16) unsigned short xs[BT * ROWP];   // ~96.5 KB bf16 x-tile
    __shared__ float t_red[BT];
    int tid = threadIdx.x;
    int btile = blockIdx.x;

    // stage 32 rows x 1536 fp32 -> bf16 LDS (coalesced float4 reads)
    const float4* xg = (const float4*)(x + (size_t)btile * BT * (F_NUM * D_DIM));
    #pragma unroll
    for (int c = 0; c < (BT * 384) / NTH; ++c) {
        int it = tid + c * NTH;
        int row = it / 384;
        int c4  = it % 384;
        float4 v = xg[it];
        ushort4 h; h.x=f2bf(v.x); h.y=f2bf(v.y); h.z=f2bf(v.z); h.w=f2bf(v.w);
        *(ushort4*)(&xs[row * ROWP + c4 * 4]) = h;
    }
    if (tid < BT) t_red[tid] = 0.0f;
    __syncthreads();

    int lane = tid & 63;
    int wv   = __builtin_amdgcn_readfirstlane(tid >> 6);
    int bcol = lane & 31;
    int q    = lane >> 5;
    int q8   = q * 8, q4 = q * 4;
    const unsigned short* xrow = xs + bcol * ROWP;
    int cnt = (wv < 6) ? 34 : 36;        // even in both cases

    f32x16 acc0, acc1;
    #pragma unroll
    for (int i = 0; i < 16; ++i) { acc0[i] = 0.0f; acc1[i] = 0.0f; }
    float tacc = 0.0f;

    const bf16x8* afr = (const bf16x8*)afrag;

    // per-field epilogue: d(acc0,reg r) = (r&3) + 8*(r>>2) + 4q ; acc1: +32
    auto epilogue = [&](int f) {
        int eb = f * 64 + q4;
        #pragma unroll
        for (int g = 0; g < 4; ++g) {
            ushort4 x0 = *(const ushort4*)(xrow + eb + 8 * g);
            ushort4 x1 = *(const ushort4*)(xrow + eb + 32 + 8 * g);
            tacc += acc0[4*g+0]*bf2f(x0.x) + acc0[4*g+1]*bf2f(x0.y)
                  + acc0[4*g+2]*bf2f(x0.z) + acc0[4*g+3]*bf2f(x0.w);
            tacc += acc1[4*g+0]*bf2f(x1.x) + acc1[4*g+1]*bf2f(x1.y)
                  + acc1[4*g+2]*bf2f(x1.z) + acc1[4*g+3]*bf2f(x1.w);
        }
        #pragma unroll
        for (int i = 0; i < 16; ++i) { acc0[i] = 0.0f; acc1[i] = 0.0f; }
    };

    // one "fat pair" step: 4 LDS b-frags, 8 MFMAs (2 chains x 4), then refill buf
    auto step = [&](int s, bf16x8* buf) {
        int e = gtab.ent[wv][s];
        int j = (e >> 9) & 31;
        int f = e >> 14;
        const unsigned short* xb = xrow + j * 64 + q8;
        bf16x8 b0 = *(const bf16x8*)(xb);
        bf16x8 b1 = *(const bf16x8*)(xb + 16);
        bf16x8 b2 = *(const bf16x8*)(xb + 32);
        bf16x8 b3 = *(const bf16x8*)(xb + 48);
        acc0 = __builtin_amdgcn_mfma_f32_32x32x16_bf16(buf[0], b0, acc0, 0, 0, 0);
        acc1 = __builtin_amdgcn_mfma_f32_32x32x16_bf16(buf[1], b0, acc1, 0, 0, 0);
        acc0 = __builtin_amdgcn_mfma_f32_32x32x16_bf16(buf[2], b1, acc0, 0, 0, 0);
        acc1 = __builtin_amdgcn_mfma_f32_32x32x16_bf16(buf[3], b1, acc1, 0, 0, 0);
        acc0 = __builtin_amdgcn_mfma_f32_32x32x16_bf16(buf[4], b2, acc0, 0, 0, 0);
        acc1 = __builtin_amdgcn_mfma_f32_32x32x16_bf16(buf[5], b2, acc1, 0, 0, 0);
        acc0 = __builtin_amdgcn_mfma_f32_32x32x16_bf16(buf[6], b3, acc0, 0, 0, 0);
        acc1 = __builtin_amdgcn_mfma_f32_32x32x16_bf16(buf[7], b3, acc1, 0, 0, 0);
        // depth-2 prefetch: refill this buffer for step s+2
        int sp = (s + 2 < cnt) ? s + 2 : cnt - 1;
        int pp = gtab.ent[wv][sp] & 511;
        const bf16x8* ap = afr + (size_t)pp * 512 + lane;
        #pragma unroll
        for (int u = 0; u < 8; ++u) buf[u] = ap[u * 64];
        if (j == 23) epilogue(f);        // wave-uniform branch
    };

    bf16x8 bufA[8], bufB[8];
    {
        int p0 = gtab.ent[wv][0] & 511;
        const bf16x8* ap = afr + (size_t)p0 * 512 + lane;
        #pragma unroll
        for (int u = 0; u < 8; ++u) bufA[u] = ap[u * 64];
        int p1 = gtab.ent[wv][1] & 511;
        ap = afr + (size_t)p1 * 512 + lane;
        #pragma unroll
        for (int u = 0; u < 8; ++u) bufB[u] = ap[u * 64];
    }

    for (int s = 0; s < cnt; s += 2) {   // ping-pong, no register rotation
        step(s,     bufA);
        step(s + 1, bufB);
    }

    atomicAdd(&t_red[bcol], tacc);
    __syncthreads();
    if (tid < BT) out[(size_t)btile * BT + tid] = t_red[tid];
}

extern "C" void kernel_launch(void* const* d_in, const int* in_sizes, int n_in,
                              void* d_out, int out_size, void* d_ws, size_t ws_size,
                              hipStream_t stream) {
    const float* x = (const float*)d_in[0];
    const float* W = (const float*)d_in[1];
    float* out = (float*)d_out;
    unsigned short* afrag = (unsigned short*)d_ws;   // 2.26 MB scratch
    wprep<<<P_NUM, 256, 0, stream>>>(W, afrag);
    fmfm_main<<<B_TOT / BT, NTH, 0, stream>>>(x, afrag, out);
}